// Round 5
// baseline (14.173 us; speedup 1.0000x reference)
//
#include <hip/hip_runtime.h>

// out[n,c,h,w] = sum over valid (i,j) in 3x3 of max(x[n,c,h,w], thr[c, 3*i+j])
// valid: i=0 iff h<111, i=2 iff h>0 (i=1 always); j=0 iff w<111, j=2 iff w>0.
// (unfold -> max -> fold overlap-add collapses to a pure elementwise op.)
//
// Occupancy variant: one block per (n,c) plane (thr stays scalar), float2
// granularity -> 6272 float2/plane = 896 threads x 7, 14 waves/block,
// 2 blocks/CU = 28 waves/CU (vs 14 in the float4 version). All 7 loads
// issued before any compute for MLP.

#define NH 112
#define WQ2 56              // 112 / 2 (float2 per row)
#define PLANE_F2 (NH * WQ2) // 6272
#define TPB 896
#define PER_T 7

__global__ __launch_bounds__(TPB, 7) void convblock_kernel(
    const float* __restrict__ x, const float* __restrict__ thr,
    float* __restrict__ out) {
  const int plane = blockIdx.x;   // n*64 + c (block-uniform)
  const int c = plane & 63;

  float t[9];
#pragma unroll
  for (int k = 0; k < 9; ++k) t[k] = thr[c * 9 + k];

  const float2* __restrict__ xin =
      reinterpret_cast<const float2*>(x) + (size_t)plane * PLANE_F2;
  float2* __restrict__ xout =
      reinterpret_cast<float2*>(out) + (size_t)plane * PLANE_F2;

  const int tid = threadIdx.x;

  // All 7 loads in flight before any compute.
  float2 v[PER_T];
#pragma unroll
  for (int k = 0; k < PER_T; ++k) v[k] = xin[tid + k * TPB];

#pragma unroll
  for (int k = 0; k < PER_T; ++k) {
    const int idx = tid + k * TPB;
    const int h = idx / WQ2;          // 0..111
    const int wq = idx - h * WQ2;     // 0..55
    const bool rokTop = (h < NH - 1); // include row i=0
    const bool rokBot = (h > 0);      // include row i=2
    const bool w0 = (wq == 0);        // elem 0 is w==0   -> exclude j=2
    const bool wL = (wq == WQ2 - 1);  // elem 1 is w==111 -> exclude j=0

    const float vv[2] = {v[k].x, v[k].y};
    float res[2];
#pragma unroll
    for (int e = 0; e < 2; ++e) {
      const float vx = vv[e];
      const bool exclJ2 = (e == 0) && w0;
      const bool exclJ0 = (e == 1) && wL;
      float s = 0.0f;
#pragma unroll
      for (int i = 0; i < 3; ++i) {
        const float m0 = fmaxf(vx, t[3 * i + 0]);
        const float m1 = fmaxf(vx, t[3 * i + 1]);
        const float m2 = fmaxf(vx, t[3 * i + 2]);
        float r = m1;
        r += exclJ0 ? 0.0f : m0;
        r += exclJ2 ? 0.0f : m2;
        const bool rok = (i == 0) ? rokTop : (i == 2) ? rokBot : true;
        s += rok ? r : 0.0f;
      }
      res[e] = s;
    }
    xout[idx] = make_float2(res[0], res[1]);
  }
}

extern "C" void kernel_launch(void* const* d_in, const int* in_sizes, int n_in,
                              void* d_out, int out_size, void* d_ws, size_t ws_size,
                              hipStream_t stream) {
  const float* x = (const float*)d_in[0];    // (8,64,112,112) f32
  const float* thr = (const float*)d_in[1];  // (64,9) f32
  float* out = (float*)d_out;                // (8,64,112,112) f32

  convblock_kernel<<<dim3(8 * 64), TPB, 0, stream>>>(x, thr, out);
}